// Round 11
// baseline (420.865 us; speedup 1.0000x reference)
//
#include <hip/hip_runtime.h>
#include <hip/hip_fp16.h>
#include <math.h>

#define FDIM 64
#define CATDIM 192
#define CH 2048      // edges per chunk in the binning passes
#define MAXNB 1024   // max dest buckets (N<65536)
#define SCTILE 2048  // elements per block in the bh scan (nblkS <= 256)

// ============ pass H: per-chunk LDS histogram over dest buckets ============
// writes CHUNK-MAJOR: bhT[g][c][b] (contiguous per block)

__global__ __launch_bounds__(256) void k_chist(const int* __restrict__ ei0,
                                               const int* __restrict__ ei1,
                                               const int* __restrict__ ei2,
                                               int* __restrict__ bhT,  // [3][nchunks][NB]
                                               int NB, int nchunks, int E) {
    __shared__ int hist[MAXNB];
    const int c = blockIdx.x, g = blockIdx.y, tid = threadIdx.x;
    const int* dest = (g == 0 ? ei0 : g == 1 ? ei1 : ei2) + E;
    const size_t L = (size_t)NB * nchunks;

    for (int i = tid; i < NB; i += 256) hist[i] = 0;
    __syncthreads();

    const int lo = c * CH, hi = min(E, lo + CH);
    for (int i = lo + tid; i < hi; i += 256) atomicAdd(&hist[dest[i] >> 6], 1);
    __syncthreads();

    for (int i = tid; i < NB; i += 256)
        bhT[g * L + (size_t)c * NB + i] = hist[i];
}

// ============ 32x32 LDS tile transpose: out[c][r] = in[r][c], per graph ============

__global__ __launch_bounds__(256) void k_tr(const int* __restrict__ in,
                                            int* __restrict__ out,
                                            int rows, int cols) {
    __shared__ int tile[32][33];
    const int g = blockIdx.z;
    const int c0 = blockIdx.x * 32;
    const int r0 = blockIdx.y * 32;
    const int tx = threadIdx.x & 31, ty0 = threadIdx.x >> 5;   // 32x8
    const size_t L = (size_t)rows * cols;
    const int* pin = in + (size_t)g * L;
    int* pout = out + (size_t)g * L;

    for (int dy = 0; dy < 32; dy += 8) {
        int r = r0 + ty0 + dy, c = c0 + tx;
        tile[ty0 + dy][tx] = (r < rows && c < cols) ? pin[(size_t)r * cols + c] : 0;
    }
    __syncthreads();
    for (int dy = 0; dy < 32; dy += 8) {
        int c = c0 + ty0 + dy, r = r0 + tx;
        if (c < cols && r < rows) pout[(size_t)c * rows + r] = tile[tx][ty0 + dy];
    }
}

// ============ 3-phase parallel exclusive scan of bh (bucket-major) per graph ============

__global__ __launch_bounds__(256) void k_scan_a(const int* __restrict__ bh,
                                                int* __restrict__ bsum,   // [3][nblkS]
                                                int L, int nblkS) {
    __shared__ int s[256];
    const int b = blockIdx.x, g = blockIdx.y, tid = threadIdx.x;
    const int* data = bh + (size_t)g * L;
    const int base = b * SCTILE + tid * 8;
    int v = 0;
#pragma unroll
    for (int j = 0; j < 8; ++j) {
        int idx = base + j;
        if (idx < L) v += data[idx];
    }
    s[tid] = v;
    __syncthreads();
    for (int d = 128; d > 0; d >>= 1) {
        if (tid < d) s[tid] += s[tid + d];
        __syncthreads();
    }
    if (tid == 0) bsum[g * nblkS + b] = s[0];
}

__global__ __launch_bounds__(256) void k_scan_b(int* __restrict__ bsum, int nblkS) {
    __shared__ int s[256];
    const int g = blockIdx.x, tid = threadIdx.x;
    int v = (tid < nblkS) ? bsum[g * nblkS + tid] : 0;
    s[tid] = v;
    __syncthreads();
    for (int d = 1; d < 256; d <<= 1) {
        int t = (tid >= d) ? s[tid - d] : 0;
        __syncthreads();
        s[tid] += t;
        __syncthreads();
    }
    if (tid < nblkS) bsum[g * nblkS + tid] = s[tid] - v;   // exclusive
}

// scan_c also emits bucket bases (folds old k_bbase): element idx%nchunks==0
// is bucket (idx/nchunks)'s first chunk -> its exclusive prefix = bucket base.

__global__ __launch_bounds__(256) void k_scan_c(int* __restrict__ bh,
                                                const int* __restrict__ bsum,
                                                int* __restrict__ bbase,   // [3][NB+1]
                                                int L, int nblkS,
                                                int NB, int nchunks, int E) {
    __shared__ int s[256];
    const int b = blockIdx.x, g = blockIdx.y, tid = threadIdx.x;
    int* data = bh + (size_t)g * L;
    const int base = b * SCTILE + tid * 8;

    int e[8];
    int tot = 0;
#pragma unroll
    for (int j = 0; j < 8; ++j) {
        e[j] = (base + j < L) ? data[base + j] : 0;
        tot += e[j];
    }
    s[tid] = tot;
    __syncthreads();
    for (int d = 1; d < 256; d <<= 1) {
        int t = (tid >= d) ? s[tid - d] : 0;
        __syncthreads();
        s[tid] += t;
        __syncthreads();
    }
    int run = bsum[g * nblkS + b] + s[tid] - tot;
#pragma unroll
    for (int j = 0; j < 8; ++j) {
        int idx = base + j;
        if (idx < L) {
            int v = e[j];
            data[idx] = run;
            if (idx % nchunks == 0) bbase[g * (NB + 1) + idx / nchunks] = run;
            run += v;
        }
    }
    if (b == 0 && tid == 0) bbase[g * (NB + 1) + NB] = E;
}

// ============ pass F: deterministic binned scatter (LDS cursors only) ============

__global__ __launch_bounds__(256) void k_cfill(const int* __restrict__ ei0,
                                               const int* __restrict__ ei1,
                                               const int* __restrict__ ei2,
                                               const float* __restrict__ w1,
                                               const float* __restrict__ w2,
                                               const int* __restrict__ bhT2, // [3][nchunks][NB] scanned bases
                                               int2* __restrict__ barr,      // [3][E]
                                               int NB, int nchunks, int E) {
    __shared__ int cur[MAXNB];
    const int c = blockIdx.x, g = blockIdx.y, tid = threadIdx.x;
    const int* e = (g == 0 ? ei0 : g == 1 ? ei1 : ei2);
    const float* w = (g == 1 ? w1 : w2);
    const int* srcp = e;
    const int* dest = e + E;
    int2* bout = barr + (size_t)g * E;
    const size_t L = (size_t)NB * nchunks;

    for (int i = tid; i < NB; i += 256)
        cur[i] = bhT2[g * L + (size_t)c * NB + i];
    __syncthreads();

    const int lo = c * CH, hi = min(E, lo + CH);
    for (int i = lo + tid; i < hi; i += 256) {
        int d = dest[i];
        int slot = atomicAdd(&cur[d >> 6], 1);
        float wv = (g == 0) ? 0.f : w[i];
        bout[slot] = make_int2(srcp[i] | ((d & 63) << 16), __float_as_int(wv));
    }
}

// ============ pass D: per-bucket degree/dis + rowptr ============

__global__ __launch_bounds__(256) void k_deg(const int2* __restrict__ barr,  // [3][E]
                                             const int* __restrict__ bbase,  // [3][NB+1]
                                             int* __restrict__ rowptr,       // [3][N+1]
                                             float* __restrict__ dis,        // [3][N]
                                             int N, int E, int NB) {
    __shared__ int hist[64];
    __shared__ float wsum[64];
    __shared__ int sc[64];

    const int b = blockIdx.x, g = blockIdx.y, tid = threadIdx.x;
    const int2* bin = barr + (size_t)g * E;
    const int beg = bbase[g * (NB + 1) + b];
    const int end = bbase[g * (NB + 1) + b + 1];

    if (tid < 64) { hist[tid] = 0; wsum[tid] = 1.0f; }   // 1.0 = self-loop weight
    __syncthreads();

    for (int t = beg + tid; t < end; t += 256) {
        int2 p = bin[t];
        int dl = (p.x >> 16) & 63;
        atomicAdd(&hist[dl], 1);
        if (g) atomicAdd(&wsum[dl], __int_as_float(p.y));
    }
    __syncthreads();

    if (tid < 64) sc[tid] = hist[tid];
    __syncthreads();
    for (int d = 1; d < 64; d <<= 1) {
        int t = 0;
        if (tid < 64 && tid >= d) t = sc[tid - d];
        __syncthreads();
        if (tid < 64) sc[tid] += t;
        __syncthreads();
    }
    if (tid < 64) {
        int node = b * 64 + tid;
        if (node < N) {
            rowptr[g * (N + 1) + node] = beg + (sc[tid] - hist[tid]);
            float s = g ? wsum[tid] : (1.0f + (float)hist[tid]);
            dis[g * N + node] = rsqrtf(s);
        }
    }
    if (b == NB - 1 && tid == 0) rowptr[g * (N + 1) + N] = end;
}

// ============ pass P: placement with fused val = w * dis[src] (fp16 packed) ============

__global__ __launch_bounds__(256) void k_place(const int2* __restrict__ barr,  // [3][E]
                                               const int* __restrict__ bbase,  // [3][NB+1]
                                               const int* __restrict__ rowptr, // [3][N+1]
                                               const float* __restrict__ dis,  // [3][N]
                                               unsigned* __restrict__ csr,     // [3][E]
                                               int N, int E, int NB) {
    __shared__ int cur[64];
    const int b = blockIdx.x, g = blockIdx.y, tid = threadIdx.x;
    const int2* bin = barr + (size_t)g * E;
    const int beg = bbase[g * (NB + 1) + b];
    const int end = bbase[g * (NB + 1) + b + 1];

    if (tid < 64) {
        int node = b * 64 + tid;
        cur[tid] = (node < N) ? rowptr[g * (N + 1) + node] - beg : 0;
    }
    __syncthreads();

    for (int t = beg + tid; t < end; t += 256) {
        int2 p = bin[t];
        int dl = (p.x >> 16) & 63;
        int pos = atomicAdd(&cur[dl], 1);
        int src = p.x & 0xFFFF;
        float wv = g ? __int_as_float(p.y) : 1.0f;
        float v = wv * dis[g * N + src];
        unsigned short wb = __half_as_ushort(__float2half(v));
        csr[(size_t)g * E + beg + pos] = (unsigned)src | ((unsigned)wb << 16);
    }
}

// ============ GEMM: out[n][64] = A[n][K] * W[64][K]^T, fp16 output ============
// W staged in KCH-wide chunks -> LDS ~34KB -> 4 blocks/CU.

template <typename T> __device__ inline float4 load4f(const T* p);
template <> __device__ inline float4 load4f<float>(const float* p) {
    return *reinterpret_cast<const float4*>(p);
}
template <> __device__ inline float4 load4f<__half>(const __half* p) {
    __half2 a = *reinterpret_cast<const __half2*>(p);
    __half2 b = *reinterpret_cast<const __half2*>(p + 2);
    float2 fa = __half22float2(a), fb = __half22float2(b);
    return make_float4(fa.x, fa.y, fb.x, fb.y);
}

template <int K, int KCH, typename TA>
__global__ __launch_bounds__(256) void k_gemm(const TA* __restrict__ A,
                                              const float* __restrict__ W,
                                              __half* __restrict__ out, int n) {
    __shared__ float wt[KCH * 65];
    __shared__ float xs[64 * 36];

    const int tid = threadIdx.x;
    const int n0 = blockIdx.x * 64;

    const int f = tid & 63;
    const int q = tid >> 6;
    float acc[16];
#pragma unroll
    for (int j = 0; j < 16; ++j) acc[j] = 0.f;

    for (int kc = 0; kc < K; kc += 32) {
        __syncthreads();   // previous chunk's readers done (xs and possibly wt)
        if ((kc % KCH) == 0) {
            for (int idx = tid; idx < FDIM * KCH; idx += 256) {
                int fr = idx / KCH;
                int kr = idx - fr * KCH;
                wt[kr * 65 + fr] = W[fr * K + kc + kr];
            }
        }
#pragma unroll
        for (int u = tid; u < 512; u += 256) {
            int node = u >> 3;
            int k4 = u & 7;
            int gn = n0 + node;
            float4 a = make_float4(0.f, 0.f, 0.f, 0.f);
            if (gn < n) a = load4f(&A[(size_t)gn * K + kc + k4 * 4]);
            *reinterpret_cast<float4*>(&xs[node * 36 + k4 * 4]) = a;
        }
        __syncthreads();

        const int kb = kc % KCH;
#pragma unroll
        for (int kk = 0; kk < 32; kk += 4) {
            float w0 = wt[(kb + kk + 0) * 65 + f];
            float w1 = wt[(kb + kk + 1) * 65 + f];
            float w2 = wt[(kb + kk + 2) * 65 + f];
            float w3 = wt[(kb + kk + 3) * 65 + f];
#pragma unroll
            for (int jj = 0; jj < 16; ++jj) {
                int j = jj * 4 + q;
                float4 av = *reinterpret_cast<const float4*>(&xs[j * 36 + kk]);
                acc[jj] = fmaf(av.x, w0, fmaf(av.y, w1, fmaf(av.z, w2, fmaf(av.w, w3, acc[jj]))));
            }
        }
    }

#pragma unroll
    for (int jj = 0; jj < 16; ++jj) {
        int node = n0 + jj * 4 + q;
        if (node < n) out[(size_t)node * FDIM + f] = __float2half(acc[jj]);
    }
}

// ============ fused dgconv gather x3 + self-loop + bias + relu [+ conv/log_softmax] ============
// one 64-lane wave per node. lane = (ep, fp): ep = lane>>5 selects edge parity,
// fp = lane&31 selects a feature PAIR (one 4B half2 load covers 2 features).
// CSR walk wave-uniform (s_load), per slot one v_cndmask picks the ep entry.
// 8 edges per main iteration = 4 loads/lane in flight. Cross-ep combine via
// shfl_xor(32). FUSE=1: conv(16x192)+log_softmax epilogue in LDS, skip cat.

template <int FUSE>
__global__ __launch_bounds__(256) void k_gather(const __half* __restrict__ h,
                                                const float* __restrict__ dis,     // [3][N]
                                                const int* __restrict__ rowptr,    // [3][N+1]
                                                const unsigned* __restrict__ csr,  // [3][E]
                                                const float* __restrict__ bias,    // [64]
                                                __half* __restrict__ cat,          // [N][192] (FUSE=0)
                                                const float* __restrict__ convw,   // [16][192] (FUSE=1)
                                                const float* __restrict__ convb,   // [16]
                                                float* __restrict__ outp,          // [N][16]
                                                int N, int E) {
    __shared__ float wl[FUSE ? 16 * 196 : 1];
    __shared__ float bl[FUSE ? 16 : 1];
    __shared__ float scratch[FUSE ? 4 : 1][FUSE ? 192 : 1];

    const int tid = threadIdx.x;
    if (FUSE) {
        for (int t = tid; t < 16 * 192; t += 256) {
            int o = t / 192;
            int k = t - o * 192;
            wl[o * 196 + k] = convw[t];
        }
        if (tid < 16) bl[tid] = convb[tid];
        __syncthreads();
    }

    const int wv = tid >> 6;
    const int lane = tid & 63;
    const int fp = lane & 31;    // feature pair index
    const int ep = lane >> 5;    // edge parity
    const int i = blockIdx.x * 4 + wv;
    if (i >= N) return;

    const __half2* h2 = reinterpret_cast<const __half2*>(h);
    float2 hv = __half22float2(h2[(size_t)i * 32 + fp]);
    const float b0 = bias[2 * fp];
    const float b1 = bias[2 * fp + 1];

    float res0[3], res1[3];

#pragma unroll
    for (int g = 0; g < 3; ++g) {
        const int* rp = rowptr + g * (N + 1);
        const unsigned* cg = csr + (size_t)g * E;
        const int beg = __builtin_amdgcn_readfirstlane(rp[i]);
        const int end = __builtin_amdgcn_readfirstlane(rp[i + 1]);
        const float dg = dis[g * N + i];

        float ax0 = 0.f, ay0 = 0.f, ax1 = 0.f, ay1 = 0.f;
        float ax2 = 0.f, ay2 = 0.f, ax3 = 0.f, ay3 = 0.f;
        int j = beg;
        for (; j + 8 <= end; j += 8) {
            unsigned u0 = ep ? cg[j + 1] : cg[j + 0];
            unsigned u1 = ep ? cg[j + 3] : cg[j + 2];
            unsigned u2 = ep ? cg[j + 5] : cg[j + 4];
            unsigned u3 = ep ? cg[j + 7] : cg[j + 6];
            float2 A0 = __half22float2(h2[(size_t)(u0 & 0xFFFFu) * 32 + fp]);
            float2 A1 = __half22float2(h2[(size_t)(u1 & 0xFFFFu) * 32 + fp]);
            float2 A2 = __half22float2(h2[(size_t)(u2 & 0xFFFFu) * 32 + fp]);
            float2 A3 = __half22float2(h2[(size_t)(u3 & 0xFFFFu) * 32 + fp]);
            float w0 = __half2float(__ushort_as_half((unsigned short)(u0 >> 16)));
            float w1 = __half2float(__ushort_as_half((unsigned short)(u1 >> 16)));
            float w2 = __half2float(__ushort_as_half((unsigned short)(u2 >> 16)));
            float w3 = __half2float(__ushort_as_half((unsigned short)(u3 >> 16)));
            ax0 = fmaf(w0, A0.x, ax0); ay0 = fmaf(w0, A0.y, ay0);
            ax1 = fmaf(w1, A1.x, ax1); ay1 = fmaf(w1, A1.y, ay1);
            ax2 = fmaf(w2, A2.x, ax2); ay2 = fmaf(w2, A2.y, ay2);
            ax3 = fmaf(w3, A3.x, ax3); ay3 = fmaf(w3, A3.y, ay3);
        }
        if (j + 4 <= end) {
            unsigned u0 = ep ? cg[j + 1] : cg[j + 0];
            unsigned u1 = ep ? cg[j + 3] : cg[j + 2];
            float2 A0 = __half22float2(h2[(size_t)(u0 & 0xFFFFu) * 32 + fp]);
            float2 A1 = __half22float2(h2[(size_t)(u1 & 0xFFFFu) * 32 + fp]);
            float w0 = __half2float(__ushort_as_half((unsigned short)(u0 >> 16)));
            float w1 = __half2float(__ushort_as_half((unsigned short)(u1 >> 16)));
            ax0 = fmaf(w0, A0.x, ax0); ay0 = fmaf(w0, A0.y, ay0);
            ax1 = fmaf(w1, A1.x, ax1); ay1 = fmaf(w1, A1.y, ay1);
            j += 4;
        }
        while (j < end) {
            unsigned ulo = cg[j];
            unsigned uhi = (j + 1 < end) ? cg[j + 1] : 0u;   // w bits 0 -> contributes 0
            unsigned u0 = ep ? uhi : ulo;
            float2 A0 = __half22float2(h2[(size_t)(u0 & 0xFFFFu) * 32 + fp]);
            float w0 = __half2float(__ushort_as_half((unsigned short)(u0 >> 16)));
            ax0 = fmaf(w0, A0.x, ax0); ay0 = fmaf(w0, A0.y, ay0);
            j += 2;
        }

        float sx = (ax0 + ax1) + (ax2 + ax3);
        float sy = (ay0 + ay1) + (ay2 + ay3);
        sx += __shfl_xor(sx, 32);
        sy += __shfl_xor(sy, 32);
        float r0 = fmaf(dg, sx, dg * dg * hv.x) + b0;
        float r1 = fmaf(dg, sy, dg * dg * hv.y) + b1;
        res0[g] = r0 > 0.f ? r0 : 0.f;
        res1[g] = r1 > 0.f ? r1 : 0.f;
    }

    if (!FUSE) {
        if (ep == 0) {
            __half2* c2 = reinterpret_cast<__half2*>(cat);
#pragma unroll
            for (int g = 0; g < 3; ++g)
                c2[(size_t)i * 96 + g * 32 + fp] = __floats2half2_rn(res0[g], res1[g]);
        }
    } else {
        if (ep == 0) {
            float2* sp = reinterpret_cast<float2*>(&scratch[wv][0]);
#pragma unroll
            for (int g = 0; g < 3; ++g)
                sp[g * 32 + fp] = make_float2(res0[g], res1[g]);
        }
        // same-wave LDS write->read: ordered by lgkmcnt, no barrier needed
        const int o = lane & 15;
        const int seg = lane >> 4;
        const float* xr = &scratch[wv][seg * 48];
        const float* wr = &wl[o * 196 + seg * 48];
        float acc = 0.f;
#pragma unroll
        for (int k4 = 0; k4 < 12; ++k4) {
            float4 xv = *reinterpret_cast<const float4*>(xr + k4 * 4);
            float4 wv4 = *reinterpret_cast<const float4*>(wr + k4 * 4);
            acc += xv.x * wv4.x + xv.y * wv4.y + xv.z * wv4.z + xv.w * wv4.w;
        }
        acc += __shfl_xor(acc, 16);
        acc += __shfl_xor(acc, 32);
        acc += bl[o];
        float m = acc;
        m = fmaxf(m, __shfl_xor(m, 1));
        m = fmaxf(m, __shfl_xor(m, 2));
        m = fmaxf(m, __shfl_xor(m, 4));
        m = fmaxf(m, __shfl_xor(m, 8));
        float s = __expf(acc - m);
        s += __shfl_xor(s, 1);
        s += __shfl_xor(s, 2);
        s += __shfl_xor(s, 4);
        s += __shfl_xor(s, 8);
        if (lane < 16) outp[(size_t)i * 16 + o] = acc - m - logf(s);
    }
}

// ============ launch ============

extern "C" void kernel_launch(void* const* d_in, const int* in_sizes, int n_in,
                              void* d_out, int out_size, void* d_ws, size_t ws_size,
                              hipStream_t stream) {
    const float* x      = (const float*)d_in[0];
    const int*   ei     = (const int*)d_in[1];
    const int*   e_in   = (const int*)d_in[2];
    const int*   e_out  = (const int*)d_in[3];
    const float* in_w   = (const float*)d_in[4];
    const float* out_w  = (const float*)d_in[5];
    const float* lin1_w = (const float*)d_in[6];
    const float* lin2_w = (const float*)d_in[7];
    const float* bias1  = (const float*)d_in[8];
    const float* bias2  = (const float*)d_in[9];
    const float* conv_w = (const float*)d_in[10];
    const float* conv_b = (const float*)d_in[11];
    float* out = (float*)d_out;

    const int N = in_sizes[0] / 128;
    const int E = in_sizes[1] / 2;
    const int NB = (N + 63) >> 6;              // dest buckets of 64 nodes
    const int nchunks = (E + CH - 1) / CH;
    const int L = NB * nchunks;
    const int nblkS = (L + SCTILE - 1) / SCTILE;   // <=256 for this problem size

    // workspace layout (4B units; wider types kept 8B/16B aligned)
    float* ws = (float*)d_ws;
    size_t o = 0;
    float* dis    = ws + o;            o += (size_t)3 * N;
    int*   rowptr = (int*)(ws + o);    o += ((size_t)3 * (N + 1) + 1) & ~1ull;
    int*   bbase  = (int*)(ws + o);    o += ((size_t)3 * (NB + 1) + 1) & ~1ull;
    int*   bsum   = (int*)(ws + o);    o += ((size_t)3 * nblkS + 1) & ~1ull;
    int*   bh     = (int*)(ws + o);    o += ((size_t)3 * L + 3) & ~3ull;   // bucket-major
    int*   bhT    = (int*)(ws + o);    o += ((size_t)3 * L + 3) & ~3ull;   // chunk-major
    __half* h     = (__half*)(ws + o); o += (size_t)N * (FDIM / 2);        // fp16
    o = (o + 3) & ~3ull;
    unsigned* csr = (unsigned*)(ws + o); o += (size_t)3 * E;               // 4B packed
    o = (o + 3) & ~3ull;
    __half* cat   = (__half*)(ws + o); o += (size_t)N * (CATDIM / 2);      // fp16
    int2*  barr   = (int2*)cat;        // alias: bucket array dead before cat written

    const int B = 256;

    // CSR build: deterministic two-pass binning (no global atomics)
    hipLaunchKernelGGL(k_chist, dim3(nchunks, 3), dim3(B), 0, stream, ei, e_in, e_out, bhT, NB, nchunks, E);
    hipLaunchKernelGGL(k_tr, dim3((NB + 31) / 32, (nchunks + 31) / 32, 3), dim3(B), 0, stream,
                       bhT, bh, nchunks, NB);                                   // -> bucket-major
    hipLaunchKernelGGL(k_scan_a, dim3(nblkS, 3), dim3(B), 0, stream, bh, bsum, L, nblkS);
    hipLaunchKernelGGL(k_scan_b, dim3(3), dim3(B), 0, stream, bsum, nblkS);
    hipLaunchKernelGGL(k_scan_c, dim3(nblkS, 3), dim3(B), 0, stream, bh, bsum, bbase, L, nblkS, NB, nchunks, E);
    hipLaunchKernelGGL(k_tr, dim3((nchunks + 31) / 32, (NB + 31) / 32, 3), dim3(B), 0, stream,
                       bh, bhT, NB, nchunks);                                   // -> chunk-major bases
    hipLaunchKernelGGL(k_cfill, dim3(nchunks, 3), dim3(B), 0, stream,
                       ei, e_in, e_out, in_w, out_w, bhT, barr, NB, nchunks, E);
    hipLaunchKernelGGL(k_deg, dim3(NB, 3), dim3(B), 0, stream, barr, bbase, rowptr, dis, N, E, NB);
    hipLaunchKernelGGL(k_place, dim3(NB, 3), dim3(B), 0, stream, barr, bbase, rowptr, dis, csr, N, E, NB);

    // layer 1
    hipLaunchKernelGGL((k_gemm<128, 64, float>), dim3((N + 63) / 64), dim3(B), 0, stream, x, lin1_w, h, N);
    hipLaunchKernelGGL((k_gather<0>), dim3((N + 3) / 4), dim3(B), 0, stream,
                       h, dis, rowptr, csr, bias1, cat,
                       (const float*)nullptr, (const float*)nullptr, (float*)nullptr, N, E);

    // layer 2 + fused head
    hipLaunchKernelGGL((k_gemm<192, 96, __half>), dim3((N + 63) / 64), dim3(B), 0, stream, cat, lin2_w, h, N);
    hipLaunchKernelGGL((k_gather<1>), dim3((N + 3) / 4), dim3(B), 0, stream,
                       h, dis, rowptr, csr, bias2, (__half*)nullptr,
                       conv_w, conv_b, out, N, E);
}

// Round 12
// 393.276 us; speedup vs baseline: 1.0702x; 1.0702x over previous
//
#include <hip/hip_runtime.h>
#include <hip/hip_fp16.h>
#include <math.h>

#define FDIM 64
#define CATDIM 192
#define CH 2048      // edges per chunk in the binning passes (high occupancy)
#define MAXNB 1024   // max dest buckets (N<65536)
#define SCTILE 2048  // elements per block in the bh scan (nblkS <= 256)

// ============ pass H: per-chunk LDS histogram over dest buckets ============
// writes BUCKET-MAJOR bh[g][b][c]; scattered 4B writes are L2-resident (bh ~3.5MB)

__global__ __launch_bounds__(256) void k_chist(const int* __restrict__ ei0,
                                               const int* __restrict__ ei1,
                                               const int* __restrict__ ei2,
                                               int* __restrict__ bh,   // [3][NB][nchunks]
                                               int NB, int nchunks, int E) {
    __shared__ int hist[MAXNB];
    const int c = blockIdx.x, g = blockIdx.y, tid = threadIdx.x;
    const int* dest = (g == 0 ? ei0 : g == 1 ? ei1 : ei2) + E;

    for (int i = tid; i < NB; i += 256) hist[i] = 0;
    __syncthreads();

    const int lo = c * CH, hi = min(E, lo + CH);
    for (int i = lo + tid; i < hi; i += 256) atomicAdd(&hist[dest[i] >> 6], 1);
    __syncthreads();

    for (int i = tid; i < NB; i += 256)
        bh[((size_t)g * NB + i) * nchunks + c] = hist[i];
}

// ============ 3-phase parallel exclusive scan of bh (bucket-major) per graph ============

__global__ __launch_bounds__(256) void k_scan_a(const int* __restrict__ bh,
                                                int* __restrict__ bsum,   // [3][nblkS]
                                                int L, int nblkS) {
    __shared__ int s[256];
    const int b = blockIdx.x, g = blockIdx.y, tid = threadIdx.x;
    const int* data = bh + (size_t)g * L;
    const int base = b * SCTILE + tid * 8;
    int v = 0;
#pragma unroll
    for (int j = 0; j < 8; ++j) {
        int idx = base + j;
        if (idx < L) v += data[idx];
    }
    s[tid] = v;
    __syncthreads();
    for (int d = 128; d > 0; d >>= 1) {
        if (tid < d) s[tid] += s[tid + d];
        __syncthreads();
    }
    if (tid == 0) bsum[g * nblkS + b] = s[0];
}

__global__ __launch_bounds__(256) void k_scan_b(int* __restrict__ bsum, int nblkS) {
    __shared__ int s[256];
    const int g = blockIdx.x, tid = threadIdx.x;
    int v = (tid < nblkS) ? bsum[g * nblkS + tid] : 0;
    s[tid] = v;
    __syncthreads();
    for (int d = 1; d < 256; d <<= 1) {
        int t = (tid >= d) ? s[tid - d] : 0;
        __syncthreads();
        s[tid] += t;
        __syncthreads();
    }
    if (tid < nblkS) bsum[g * nblkS + tid] = s[tid] - v;   // exclusive
}

// scan_c also emits bucket bases: element idx%nchunks==0 is bucket idx/nchunks's
// first chunk -> its exclusive prefix = bucket base.

__global__ __launch_bounds__(256) void k_scan_c(int* __restrict__ bh,
                                                const int* __restrict__ bsum,
                                                int* __restrict__ bbase,   // [3][NB+1]
                                                int L, int nblkS,
                                                int NB, int nchunks, int E) {
    __shared__ int s[256];
    const int b = blockIdx.x, g = blockIdx.y, tid = threadIdx.x;
    int* data = bh + (size_t)g * L;
    const int base = b * SCTILE + tid * 8;

    int e[8];
    int tot = 0;
#pragma unroll
    for (int j = 0; j < 8; ++j) {
        e[j] = (base + j < L) ? data[base + j] : 0;
        tot += e[j];
    }
    s[tid] = tot;
    __syncthreads();
    for (int d = 1; d < 256; d <<= 1) {
        int t = (tid >= d) ? s[tid - d] : 0;
        __syncthreads();
        s[tid] += t;
        __syncthreads();
    }
    int run = bsum[g * nblkS + b] + s[tid] - tot;
#pragma unroll
    for (int j = 0; j < 8; ++j) {
        int idx = base + j;
        if (idx < L) {
            int v = e[j];
            data[idx] = run;
            if (idx % nchunks == 0) bbase[g * (NB + 1) + idx / nchunks] = run;
            run += v;
        }
    }
    if (b == 0 && tid == 0) bbase[g * (NB + 1) + NB] = E;
}

// ============ pass F: deterministic binned scatter (LDS cursors only) ============
// cursor bases read strided from scanned bh — L2-resident, latency hidden by occupancy.

__global__ __launch_bounds__(256) void k_cfill(const int* __restrict__ ei0,
                                               const int* __restrict__ ei1,
                                               const int* __restrict__ ei2,
                                               const float* __restrict__ w1,
                                               const float* __restrict__ w2,
                                               const int* __restrict__ bhs,  // [3][NB][nchunks] scanned
                                               int2* __restrict__ barr,      // [3][E]
                                               int NB, int nchunks, int E) {
    __shared__ int cur[MAXNB];
    const int c = blockIdx.x, g = blockIdx.y, tid = threadIdx.x;
    const int* e = (g == 0 ? ei0 : g == 1 ? ei1 : ei2);
    const float* w = (g == 1 ? w1 : w2);
    const int* srcp = e;
    const int* dest = e + E;
    int2* bout = barr + (size_t)g * E;

    for (int i = tid; i < NB; i += 256)
        cur[i] = bhs[((size_t)g * NB + i) * nchunks + c];
    __syncthreads();

    const int lo = c * CH, hi = min(E, lo + CH);
    for (int i = lo + tid; i < hi; i += 256) {
        int d = dest[i];
        int slot = atomicAdd(&cur[d >> 6], 1);
        float wv = (g == 0) ? 0.f : w[i];
        bout[slot] = make_int2(srcp[i] | ((d & 63) << 16), __float_as_int(wv));
    }
}

// ============ pass D: per-bucket degree/dis + rowptr ============

__global__ __launch_bounds__(256) void k_deg(const int2* __restrict__ barr,  // [3][E]
                                             const int* __restrict__ bbase,  // [3][NB+1]
                                             int* __restrict__ rowptr,       // [3][N+1]
                                             float* __restrict__ dis,        // [3][N]
                                             int N, int E, int NB) {
    __shared__ int hist[64];
    __shared__ float wsum[64];
    __shared__ int sc[64];

    const int b = blockIdx.x, g = blockIdx.y, tid = threadIdx.x;
    const int2* bin = barr + (size_t)g * E;
    const int beg = bbase[g * (NB + 1) + b];
    const int end = bbase[g * (NB + 1) + b + 1];

    if (tid < 64) { hist[tid] = 0; wsum[tid] = 1.0f; }   // 1.0 = self-loop weight
    __syncthreads();

    for (int t = beg + tid; t < end; t += 256) {
        int2 p = bin[t];
        int dl = (p.x >> 16) & 63;
        atomicAdd(&hist[dl], 1);
        if (g) atomicAdd(&wsum[dl], __int_as_float(p.y));
    }
    __syncthreads();

    if (tid < 64) sc[tid] = hist[tid];
    __syncthreads();
    for (int d = 1; d < 64; d <<= 1) {
        int t = 0;
        if (tid < 64 && tid >= d) t = sc[tid - d];
        __syncthreads();
        if (tid < 64) sc[tid] += t;
        __syncthreads();
    }
    if (tid < 64) {
        int node = b * 64 + tid;
        if (node < N) {
            rowptr[g * (N + 1) + node] = beg + (sc[tid] - hist[tid]);
            float s = g ? wsum[tid] : (1.0f + (float)hist[tid]);
            dis[g * N + node] = rsqrtf(s);
        }
    }
    if (b == NB - 1 && tid == 0) rowptr[g * (N + 1) + N] = end;
}

// ============ pass P: placement with fused val = w * dis[src] (fp16 packed) ============

__global__ __launch_bounds__(256) void k_place(const int2* __restrict__ barr,  // [3][E]
                                               const int* __restrict__ bbase,  // [3][NB+1]
                                               const int* __restrict__ rowptr, // [3][N+1]
                                               const float* __restrict__ dis,  // [3][N]
                                               unsigned* __restrict__ csr,     // [3][E]
                                               int N, int E, int NB) {
    __shared__ int cur[64];
    const int b = blockIdx.x, g = blockIdx.y, tid = threadIdx.x;
    const int2* bin = barr + (size_t)g * E;
    const int beg = bbase[g * (NB + 1) + b];
    const int end = bbase[g * (NB + 1) + b + 1];

    if (tid < 64) {
        int node = b * 64 + tid;
        cur[tid] = (node < N) ? rowptr[g * (N + 1) + node] - beg : 0;
    }
    __syncthreads();

    for (int t = beg + tid; t < end; t += 256) {
        int2 p = bin[t];
        int dl = (p.x >> 16) & 63;
        int pos = atomicAdd(&cur[dl], 1);
        int src = p.x & 0xFFFF;
        float wv = g ? __int_as_float(p.y) : 1.0f;
        float v = wv * dis[g * N + src];
        unsigned short wb = __half_as_ushort(__float2half(v));
        csr[(size_t)g * E + beg + pos] = (unsigned)src | ((unsigned)wb << 16);
    }
}

// ============ GEMM: out[n][64] = A[n][K] * W[64][K]^T, fp16 output ============
// W staged in KCH-wide chunks -> LDS ~34KB -> 4 blocks/CU.

template <typename T> __device__ inline float4 load4f(const T* p);
template <> __device__ inline float4 load4f<float>(const float* p) {
    return *reinterpret_cast<const float4*>(p);
}
template <> __device__ inline float4 load4f<__half>(const __half* p) {
    __half2 a = *reinterpret_cast<const __half2*>(p);
    __half2 b = *reinterpret_cast<const __half2*>(p + 2);
    float2 fa = __half22float2(a), fb = __half22float2(b);
    return make_float4(fa.x, fa.y, fb.x, fb.y);
}

template <int K, int KCH, typename TA>
__global__ __launch_bounds__(256) void k_gemm(const TA* __restrict__ A,
                                              const float* __restrict__ W,
                                              __half* __restrict__ out, int n) {
    __shared__ float wt[KCH * 65];
    __shared__ float xs[64 * 36];

    const int tid = threadIdx.x;
    const int n0 = blockIdx.x * 64;

    const int f = tid & 63;
    const int q = tid >> 6;
    float acc[16];
#pragma unroll
    for (int j = 0; j < 16; ++j) acc[j] = 0.f;

    for (int kc = 0; kc < K; kc += 32) {
        __syncthreads();
        if ((kc % KCH) == 0) {
            for (int idx = tid; idx < FDIM * KCH; idx += 256) {
                int fr = idx / KCH;
                int kr = idx - fr * KCH;
                wt[kr * 65 + fr] = W[fr * K + kc + kr];
            }
        }
#pragma unroll
        for (int u = tid; u < 512; u += 256) {
            int node = u >> 3;
            int k4 = u & 7;
            int gn = n0 + node;
            float4 a = make_float4(0.f, 0.f, 0.f, 0.f);
            if (gn < n) a = load4f(&A[(size_t)gn * K + kc + k4 * 4]);
            *reinterpret_cast<float4*>(&xs[node * 36 + k4 * 4]) = a;
        }
        __syncthreads();

        const int kb = kc % KCH;
#pragma unroll
        for (int kk = 0; kk < 32; kk += 4) {
            float w0 = wt[(kb + kk + 0) * 65 + f];
            float w1 = wt[(kb + kk + 1) * 65 + f];
            float w2 = wt[(kb + kk + 2) * 65 + f];
            float w3 = wt[(kb + kk + 3) * 65 + f];
#pragma unroll
            for (int jj = 0; jj < 16; ++jj) {
                int j = jj * 4 + q;
                float4 av = *reinterpret_cast<const float4*>(&xs[j * 36 + kk]);
                acc[jj] = fmaf(av.x, w0, fmaf(av.y, w1, fmaf(av.z, w2, fmaf(av.w, w3, acc[jj]))));
            }
        }
    }

#pragma unroll
    for (int jj = 0; jj < 16; ++jj) {
        int node = n0 + jj * 4 + q;
        if (node < n) out[(size_t)node * FDIM + f] = __float2half(acc[jj]);
    }
}

// ============ fused dgconv gather x3 + self-loop + bias + relu ============
// one 64-lane wave per node; wave-uniform CSR walk (SGPR s_loads), 8-way MLP.
// (round-9 verified core: scalar unpack, per-lane only the h-row load)

__global__ __launch_bounds__(256) void k_gather(const __half* __restrict__ h,
                                                const float* __restrict__ dis,     // [3][N]
                                                const int* __restrict__ rowptr,    // [3][N+1]
                                                const unsigned* __restrict__ csr,  // [3][E]
                                                const float* __restrict__ bias,    // [64]
                                                __half* __restrict__ cat,          // [N][192]
                                                int N, int E) {
    int i = blockIdx.x * 4 + (threadIdx.x >> 6);
    if (i >= N) return;
    const int lane = threadIdx.x & 63;

    const float hv = __half2float(h[(size_t)i * FDIM + lane]);
    const float b = bias[lane];

#pragma unroll
    for (int g = 0; g < 3; ++g) {
        const int* rp = rowptr + g * (N + 1);
        const unsigned* cg = csr + (size_t)g * E;
        const int beg = __builtin_amdgcn_readfirstlane(rp[i]);
        const int end = __builtin_amdgcn_readfirstlane(rp[i + 1]);
        float dg = dis[g * N + i];

        float acc0 = 0.f, acc1 = 0.f, acc2 = 0.f, acc3 = 0.f;
        float acc4 = 0.f, acc5 = 0.f, acc6 = 0.f, acc7 = 0.f;
        int j = beg;
        for (; j + 8 <= end; j += 8) {
            unsigned u0 = cg[j + 0];
            unsigned u1 = cg[j + 1];
            unsigned u2 = cg[j + 2];
            unsigned u3 = cg[j + 3];
            unsigned u4 = cg[j + 4];
            unsigned u5 = cg[j + 5];
            unsigned u6 = cg[j + 6];
            unsigned u7 = cg[j + 7];
            float a0 = __half2float(h[(size_t)(u0 & 0xFFFFu) * FDIM + lane]);
            float a1 = __half2float(h[(size_t)(u1 & 0xFFFFu) * FDIM + lane]);
            float a2 = __half2float(h[(size_t)(u2 & 0xFFFFu) * FDIM + lane]);
            float a3 = __half2float(h[(size_t)(u3 & 0xFFFFu) * FDIM + lane]);
            float a4 = __half2float(h[(size_t)(u4 & 0xFFFFu) * FDIM + lane]);
            float a5 = __half2float(h[(size_t)(u5 & 0xFFFFu) * FDIM + lane]);
            float a6 = __half2float(h[(size_t)(u6 & 0xFFFFu) * FDIM + lane]);
            float a7 = __half2float(h[(size_t)(u7 & 0xFFFFu) * FDIM + lane]);
            acc0 = fmaf(__half2float(__ushort_as_half((unsigned short)(u0 >> 16))), a0, acc0);
            acc1 = fmaf(__half2float(__ushort_as_half((unsigned short)(u1 >> 16))), a1, acc1);
            acc2 = fmaf(__half2float(__ushort_as_half((unsigned short)(u2 >> 16))), a2, acc2);
            acc3 = fmaf(__half2float(__ushort_as_half((unsigned short)(u3 >> 16))), a3, acc3);
            acc4 = fmaf(__half2float(__ushort_as_half((unsigned short)(u4 >> 16))), a4, acc4);
            acc5 = fmaf(__half2float(__ushort_as_half((unsigned short)(u5 >> 16))), a5, acc5);
            acc6 = fmaf(__half2float(__ushort_as_half((unsigned short)(u6 >> 16))), a6, acc6);
            acc7 = fmaf(__half2float(__ushort_as_half((unsigned short)(u7 >> 16))), a7, acc7);
        }
        if (j + 4 <= end) {
            unsigned u0 = cg[j + 0];
            unsigned u1 = cg[j + 1];
            unsigned u2 = cg[j + 2];
            unsigned u3 = cg[j + 3];
            float a0 = __half2float(h[(size_t)(u0 & 0xFFFFu) * FDIM + lane]);
            float a1 = __half2float(h[(size_t)(u1 & 0xFFFFu) * FDIM + lane]);
            float a2 = __half2float(h[(size_t)(u2 & 0xFFFFu) * FDIM + lane]);
            float a3 = __half2float(h[(size_t)(u3 & 0xFFFFu) * FDIM + lane]);
            acc0 = fmaf(__half2float(__ushort_as_half((unsigned short)(u0 >> 16))), a0, acc0);
            acc1 = fmaf(__half2float(__ushort_as_half((unsigned short)(u1 >> 16))), a1, acc1);
            acc2 = fmaf(__half2float(__ushort_as_half((unsigned short)(u2 >> 16))), a2, acc2);
            acc3 = fmaf(__half2float(__ushort_as_half((unsigned short)(u3 >> 16))), a3, acc3);
            j += 4;
        }
        for (; j < end; ++j) {           // wave-uniform tail (end is SGPR)
            unsigned u0 = cg[j];
            float a0 = __half2float(h[(size_t)(u0 & 0xFFFFu) * FDIM + lane]);
            acc0 = fmaf(__half2float(__ushort_as_half((unsigned short)(u0 >> 16))), a0, acc0);
        }
        float outv = dg * (((acc0 + acc1) + (acc2 + acc3)) + ((acc4 + acc5) + (acc6 + acc7)))
                   + dg * dg * hv + b;
        cat[(size_t)i * CATDIM + g * FDIM + lane] = __float2half(outv > 0.f ? outv : 0.f);
    }
}

// ============ head: pointwise conv (16 out) + log_softmax (fp16 cat) ============

__global__ __launch_bounds__(256) void k_final(const __half* __restrict__ cat,
                                               const float* __restrict__ convw,  // [16][192]
                                               const float* __restrict__ convb,  // [16]
                                               float* __restrict__ out, int n) {
    __shared__ float wl[16 * 196];
    __shared__ float bl[16];
    const int tid = threadIdx.x;
    for (int t = tid; t < 16 * 192; t += 256) {
        int o = t / 192;
        int k = t - o * 192;
        wl[o * 196 + k] = convw[t];
    }
    if (tid < 16) bl[tid] = convb[tid];
    __syncthreads();

    const int o = tid & 15;
    const int node = blockIdx.x * 16 + (tid >> 4);
    const int nc = node < n ? node : n - 1;

    const float4* xr4 = reinterpret_cast<const float4*>(cat + (size_t)nc * CATDIM);
    const float* wr = &wl[o * 196];
    float acc = bl[o];
#pragma unroll
    for (int k8 = 0; k8 < CATDIM / 8; ++k8) {
        float4 raw = xr4[k8];
        const __half2* hp = reinterpret_cast<const __half2*>(&raw);
        float2 f0 = __half22float2(hp[0]);
        float2 f1 = __half22float2(hp[1]);
        float2 f2 = __half22float2(hp[2]);
        float2 f3 = __half22float2(hp[3]);
        const float* w8 = wr + k8 * 8;
        acc += f0.x * w8[0] + f0.y * w8[1] + f1.x * w8[2] + f1.y * w8[3] +
               f2.x * w8[4] + f2.y * w8[5] + f3.x * w8[6] + f3.y * w8[7];
    }

    float m = acc;
    m = fmaxf(m, __shfl_xor(m, 1));
    m = fmaxf(m, __shfl_xor(m, 2));
    m = fmaxf(m, __shfl_xor(m, 4));
    m = fmaxf(m, __shfl_xor(m, 8));
    float s = __expf(acc - m);
    s += __shfl_xor(s, 1);
    s += __shfl_xor(s, 2);
    s += __shfl_xor(s, 4);
    s += __shfl_xor(s, 8);
    if (node < n) out[(size_t)node * 16 + o] = acc - m - logf(s);
}

// ============ launch ============

extern "C" void kernel_launch(void* const* d_in, const int* in_sizes, int n_in,
                              void* d_out, int out_size, void* d_ws, size_t ws_size,
                              hipStream_t stream) {
    const float* x      = (const float*)d_in[0];
    const int*   ei     = (const int*)d_in[1];
    const int*   e_in   = (const int*)d_in[2];
    const int*   e_out  = (const int*)d_in[3];
    const float* in_w   = (const float*)d_in[4];
    const float* out_w  = (const float*)d_in[5];
    const float* lin1_w = (const float*)d_in[6];
    const float* lin2_w = (const float*)d_in[7];
    const float* bias1  = (const float*)d_in[8];
    const float* bias2  = (const float*)d_in[9];
    const float* conv_w = (const float*)d_in[10];
    const float* conv_b = (const float*)d_in[11];
    float* out = (float*)d_out;

    const int N = in_sizes[0] / 128;
    const int E = in_sizes[1] / 2;
    const int NB = (N + 63) >> 6;              // dest buckets of 64 nodes
    const int nchunks = (E + CH - 1) / CH;
    const int L = NB * nchunks;
    const int nblkS = (L + SCTILE - 1) / SCTILE;   // <=256 for this problem size

    // workspace layout (4B units; wider types kept 8B/16B aligned)
    float* ws = (float*)d_ws;
    size_t o = 0;
    float* dis    = ws + o;            o += (size_t)3 * N;
    int*   rowptr = (int*)(ws + o);    o += ((size_t)3 * (N + 1) + 1) & ~1ull;
    int*   bbase  = (int*)(ws + o);    o += ((size_t)3 * (NB + 1) + 1) & ~1ull;
    int*   bsum   = (int*)(ws + o);    o += ((size_t)3 * nblkS + 1) & ~1ull;
    int*   bh     = (int*)(ws + o);    o += ((size_t)3 * L + 3) & ~3ull;   // bucket-major
    __half* h     = (__half*)(ws + o); o += (size_t)N * (FDIM / 2);        // fp16
    o = (o + 3) & ~3ull;
    unsigned* csr = (unsigned*)(ws + o); o += (size_t)3 * E;               // 4B packed
    o = (o + 3) & ~3ull;
    __half* cat   = (__half*)(ws + o); o += (size_t)N * (CATDIM / 2);      // fp16
    int2*  barr   = (int2*)cat;        // alias: bucket array dead before cat written

    const int B = 256;

    // CSR build: deterministic two-pass binning (no global atomics)
    hipLaunchKernelGGL(k_chist, dim3(nchunks, 3), dim3(B), 0, stream, ei, e_in, e_out, bh, NB, nchunks, E);
    hipLaunchKernelGGL(k_scan_a, dim3(nblkS, 3), dim3(B), 0, stream, bh, bsum, L, nblkS);
    hipLaunchKernelGGL(k_scan_b, dim3(3), dim3(B), 0, stream, bsum, nblkS);
    hipLaunchKernelGGL(k_scan_c, dim3(nblkS, 3), dim3(B), 0, stream, bh, bsum, bbase, L, nblkS, NB, nchunks, E);
    hipLaunchKernelGGL(k_cfill, dim3(nchunks, 3), dim3(B), 0, stream,
                       ei, e_in, e_out, in_w, out_w, bh, barr, NB, nchunks, E);
    hipLaunchKernelGGL(k_deg, dim3(NB, 3), dim3(B), 0, stream, barr, bbase, rowptr, dis, N, E, NB);
    hipLaunchKernelGGL(k_place, dim3(NB, 3), dim3(B), 0, stream, barr, bbase, rowptr, dis, csr, N, E, NB);

    // layer 1
    hipLaunchKernelGGL((k_gemm<128, 64, float>), dim3((N + 63) / 64), dim3(B), 0, stream, x, lin1_w, h, N);
    hipLaunchKernelGGL(k_gather, dim3((N + 3) / 4), dim3(B), 0, stream,
                       h, dis, rowptr, csr, bias1, cat, N, E);

    // layer 2
    hipLaunchKernelGGL((k_gemm<192, 96, __half>), dim3((N + 63) / 64), dim3(B), 0, stream, cat, lin2_w, h, N);
    hipLaunchKernelGGL(k_gather, dim3((N + 3) / 4), dim3(B), 0, stream,
                       h, dis, rowptr, csr, bias2, cat, N, E);

    // head
    hipLaunchKernelGGL(k_final, dim3((N + 15) / 16), dim3(B), 0, stream, cat, conv_w, conv_b, out, N);
}